// Round 1
// baseline (145.984 us; speedup 1.0000x reference)
//
#include <hip/hip_runtime.h>
#include <math.h>

// Problem: B=32, C=3, H=W=512. PATCH=15, p=7.
// Reference = mean_b( min_{c,h,w} input[b] ) because reflect-pad adds only
// duplicate values, so min over padded == min over original.
//
// Per batch: 3*512*512 = 786432 floats = 196608 float4.
// Stage 1: 64 blocks per batch, 256 threads, 12 float4 per thread.
// Stage 2: one 64-thread block folds 32*64 partials -> mean.

#define ELEMS_PER_BATCH 786432
#define VEC4_PER_BATCH  196608
#define BLOCKS_PER_BATCH 64
#define VEC4_PER_BLOCK  (VEC4_PER_BATCH / BLOCKS_PER_BATCH)   // 3072
#define THREADS 256
#define VEC4_PER_THREAD (VEC4_PER_BLOCK / THREADS)            // 12

__global__ __launch_bounds__(THREADS) void dcp_batch_min_partial(
        const float* __restrict__ in, float* __restrict__ partial) {
    const int b  = blockIdx.y;
    const int bx = blockIdx.x;
    const int t  = threadIdx.x;

    const float4* base = reinterpret_cast<const float4*>(in) +
                         (size_t)b * VEC4_PER_BATCH + (size_t)bx * VEC4_PER_BLOCK;

    float m = INFINITY;
#pragma unroll
    for (int i = 0; i < VEC4_PER_THREAD; ++i) {
        float4 v = base[i * THREADS + t];
        m = fminf(m, fminf(fminf(v.x, v.y), fminf(v.z, v.w)));
    }

    // wave-64 shuffle reduce (min)
#pragma unroll
    for (int off = 32; off > 0; off >>= 1)
        m = fminf(m, __shfl_down(m, off, 64));

    __shared__ float smem[THREADS / 64];
    if ((t & 63) == 0) smem[t >> 6] = m;
    __syncthreads();
    if (t == 0) {
        float r = smem[0];
#pragma unroll
        for (int w = 1; w < THREADS / 64; ++w) r = fminf(r, smem[w]);
        partial[b * BLOCKS_PER_BATCH + bx] = r;
    }
}

__global__ __launch_bounds__(64) void dcp_finalize(
        const float* __restrict__ partial, float* __restrict__ out) {
    const int t = threadIdx.x;  // 64 threads
    float v = 0.0f;
    if (t < 32) {
        float m = INFINITY;
#pragma unroll 8
        for (int i = 0; i < BLOCKS_PER_BATCH; ++i)
            m = fminf(m, partial[t * BLOCKS_PER_BATCH + i]);
        v = m;  // lanes 32..63 contribute 0 to the sum
    }
#pragma unroll
    for (int off = 32; off > 0; off >>= 1)
        v += __shfl_down(v, off, 64);
    if (t == 0) out[0] = v * (1.0f / 32.0f);
}

extern "C" void kernel_launch(void* const* d_in, const int* in_sizes, int n_in,
                              void* d_out, int out_size, void* d_ws, size_t ws_size,
                              hipStream_t stream) {
    const float* in = (const float*)d_in[0];
    float* out = (float*)d_out;
    float* partial = (float*)d_ws;  // 32*64 floats = 8 KB

    dim3 grid(BLOCKS_PER_BATCH, 32);
    dcp_batch_min_partial<<<grid, THREADS, 0, stream>>>(in, partial);
    dcp_finalize<<<1, 64, 0, stream>>>(partial, out);
}